// Round 13
// baseline (460.876 us; speedup 1.0000x reference)
//
#include <hip/hip_runtime.h>

#define TSTEPS 336
#define NI 24
#define NH 128
#define RW 16          // batch rows per workgroup
#define NTHREADS 512
#define NWG 256        // 4096 / RW

typedef __attribute__((ext_vector_type(8))) short bf16x8;
typedef __attribute__((ext_vector_type(4))) float f32x4;
typedef unsigned short u16;
typedef unsigned int u32;

struct __align__(16) Smem {
    u16 hhi[4][72][8];                  // 4608  h frags (hi only), phi-swizzled slots
    u16 chi[64][8], clo[64][8];         // 2048  c hi/lo A-frags (K-pad lanes 48-63 stay zero)
    u16 x1hi[64][8], x2hi[64][8];       // 2048  x A-frags (hi only)
    float xt[2][16][52];                // 6656  x staging, padded rows
    u16 w1f[2][4][64][8];               // 8192  W1 B-frags (head weights live in LDS now)
    u16 w2f[2][64][8];                  // 2048  W2 B-frags (K=24, zero-padded)
    u16 h2of[4][64][8];                 // 4096  h2o B-frag, col 0
};                                      // 29696 B -> 2 WG/CU LDS-wise
static_assert(sizeof(Smem) <= 32768, "LDS overflow for 2 WG/CU");

__device__ __forceinline__ u16 f2bf(float f) {
    u32 u = __float_as_uint(f);
    return (u16)((u + 0x7FFFu + ((u >> 16) & 1u)) >> 16);
}
__device__ __forceinline__ float bf2f(u16 h) { return __uint_as_float(((u32)h) << 16); }
__device__ __forceinline__ float frcp(float x) { return __builtin_amdgcn_rcpf(x); }
__device__ __forceinline__ float fex2(float x) { return __builtin_amdgcn_exp2f(x); }
__device__ __forceinline__ float sigm(float x) { return frcp(1.0f + fex2(-1.4426950408889634f * x)); }
__device__ __forceinline__ float tanhf_(float x) { return 1.0f - 2.0f * frcp(1.0f + fex2(2.8853900817779268f * x)); }
__device__ __forceinline__ float fexp(float x) { return fex2(1.4426950408889634f * x); }

// pack 8 consecutive f32 -> bf16x8 (RNE)
__device__ __forceinline__ bf16x8 ldfrag(const float* __restrict__ p) {
    float4 a = *(const float4*)p;
    float4 b = *(const float4*)(p + 4);
    union { u32 u[4]; bf16x8 v; } r;
    r.u[0] = (u32)f2bf(a.x) | ((u32)f2bf(a.y) << 16);
    r.u[1] = (u32)f2bf(a.z) | ((u32)f2bf(a.w) << 16);
    r.u[2] = (u32)f2bf(b.x) | ((u32)f2bf(b.y) << 16);
    r.u[3] = (u32)f2bf(b.z) | ((u32)f2bf(b.w) << 16);
    return r.v;
}

// LDS-only barrier: global prefetch stays in flight
__device__ __forceinline__ void bar() {
    asm volatile("s_waitcnt lgkmcnt(0)" ::: "memory");
    __builtin_amdgcn_s_barrier();
    asm volatile("" ::: "memory");
}

#define MFMA(A, B, C) __builtin_amdgcn_mfma_f32_16x16x32_bf16((A), (B), (C), 0, 0, 0)

__global__ __launch_bounds__(NTHREADS, 2) void gru_persist(
    const float* __restrict__ x, const float* __restrict__ wih, const float* __restrict__ whh,
    const float* __restrict__ bih, const float* __restrict__ bhh,
    const float* __restrict__ h2ow, const float* __restrict__ h2ob_p,
    const float* __restrict__ w1w, const float* __restrict__ w1b_p,
    const float* __restrict__ w2w, const float* __restrict__ w2b_p,
    float* __restrict__ out)
{
    __shared__ Smem S;
    const int tid = threadIdx.x;
    const int l = tid & 63;
    const int w = tid >> 6;      // wave 0..7
    const int g = l >> 4;
    const int cl = l & 15;
    const int b0 = blockIdx.x * RW;

    for (int i = tid; i < (int)(sizeof(Smem) / 4); i += NTHREADS) ((u32*)&S)[i] = 0u;
    bar();   // LDS zeroed (K-pad lanes of frags must be 0)

    // ---- head weights -> LDS fragment arrays (packed once) ----
    for (int idx = tid; idx < NI * NH; idx += NTHREADS) {           // W1 [24][128]
        int c = idx >> 7, k = idx & 127;
        S.w1f[c >> 4][k >> 5][(c & 15) + ((k >> 3) & 3) * 16][k & 7] = f2bf(w1w[idx]);
    }
    for (int idx = tid; idx < NI * NI; idx += NTHREADS) {           // W2 [24][24]
        int c = idx / NI, k = idx - c * NI;
        S.w2f[c >> 4][(c & 15) + (k >> 3) * 16][k & 7] = f2bf(w2w[idx]);
    }
    for (int k = tid; k < NH; k += NTHREADS)                        // h2o col 0
        S.h2of[k >> 5][((k >> 3) & 3) * 16][k & 7] = f2bf(h2ow[k]);
    // stage x(0) -> xt[0], x(1) -> xt[1]
    if (tid < 192) {
        int row = tid / 12, c4 = (tid % 12) * 4;
        *(float4*)&S.xt[0][row][c4] = *(const float4*)(x + ((size_t)(b0 + row) * TSTEPS) * 48 + c4);
        *(float4*)&S.xt[1][row][c4] = *(const float4*)(x + ((size_t)(b0 + row) * TSTEPS + 1) * 48 + c4);
    }

    // ---- gate weights -> persistent registers (wave w owns tiles w, w+8, w+16) ----
    const bf16x8 zf = {0, 0, 0, 0, 0, 0, 0, 0};
    bf16x8 wihR[3], whhR[3][4];
#pragma unroll
    for (int s = 0; s < 3; ++s) {
        const int tw = w + 8 * s;
        wihR[s] = (l < 48) ? ldfrag(wih + (16 * tw + cl) * NI + 8 * g) : zf;
#pragma unroll
        for (int kt = 0; kt < 4; ++kt)
            whhR[s][kt] = ldfrag(whh + (16 * tw + cl) * NH + 32 * kt + 8 * g);
    }

    // per-lane constants
    const int u = 16 * w + cl;
    const float bR  = bih[u] + bhh[u];
    const float bZ  = bih[128 + u] + bhh[128 + u];
    const float bxN = bih[256 + u];
    const float bhN = bhh[256 + u];
    const float w1b_c = (w == 0) ? w1b_p[cl] : ((w == 1 && cl < 8) ? w1b_p[16 + cl] : 0.0f);
    const float w2b_c = (w == 0) ? w2b_p[cl] : ((w == 1 && cl < 8) ? w2b_p[16 + cl] : 0.0f);
    const float h2ob = h2ob_p[0];

    // h frag addressing (phi(p) = p + ((p>>3)&1) + 2*(p>>4))
    const int ktH = w >> 1;
    const int cc = (2 * w + (cl >> 3)) & 3;
    const int hsB0 = 4 * g + 16 * cc + (g >> 1) + 2 * cc;
    const int eH = cl & 7;
    const int hsl = l + ((l >> 3) & 1) + 2 * (l >> 4);
    // in-register attention lane mapping (waves 0,1): col jC
    const int jC = 16 * w + cl;
    const int cSlotB = ((jC >> 3) & 3) * 16;
    const int cEl = jC & 7;
    const bool isC = (w == 0) || (w == 1 && cl < 8);

    float h_reg[4] = {0.f, 0.f, 0.f, 0.f};

    bar();   // packed weights + xt visible

    // c(0)=h1(0), x(0) frags (rows 0-15)
    if (tid < 384) {
        int rr = tid & 15, j = tid >> 4;
        float xh1 = S.xt[0][rr][j];
        float xh2 = S.xt[0][rr][24 + j];
        int lane = rr + (j >> 3) * 16, el = j & 7;
        u16 hi = f2bf(xh1);
        S.chi[lane][el] = hi;  S.clo[lane][el] = f2bf(xh1 - bf2f(hi));
        S.x1hi[lane][el] = hi;
        S.x2hi[lane][el] = f2bf(xh2);
    }
    // gh(0) carries = biases (h(-1)=0)
    f32x4 gR = {bR, bR, bR, bR};
    f32x4 gZ = {bZ, bZ, bZ, bZ};
    f32x4 gN = {bhN, bhN, bhN, bhN};
    __syncthreads();

    for (int t = 0; t < TSTEPS; ++t) {
        const int nxt = (t + 1) & 1;
        float4 xf;
        const bool isLd = (tid >= 320) && (t + 2 < TSTEPS);
        if (isLd) {   // issue x(t+2) load; stays in flight through P1
            int e = tid - 320, row = e / 12, c4 = (e % 12) * 4;
            xf = *(const float4*)(x + ((size_t)(b0 + row) * TSTEPS + (t + 2)) * 48 + c4);
        }
        // ---- P1: finish gates with c(t); s1/s2 MFMAs (waves 0,1); h update+store ----
        f32x4 aN = {bxN, bxN, bxN, bxN};
        f32x4 s1a, s2a;
        {
            bf16x8 cH = *(const bf16x8*)&S.chi[l][0];
            bf16x8 cL = *(const bf16x8*)&S.clo[l][0];
            gR = MFMA(cH, wihR[0], gR);  gR = MFMA(cL, wihR[0], gR);
            gZ = MFMA(cH, wihR[1], gZ);  gZ = MFMA(cL, wihR[1], gZ);
            aN = MFMA(cH, wihR[2], aN);  aN = MFMA(cL, wihR[2], aN);
        }
        if (w < 2) {
            bf16x8 w2frag = *(const bf16x8*)&S.w2f[w][l][0];
            bf16x8 x1f = *(const bf16x8*)&S.x1hi[l][0];
            bf16x8 x2f = *(const bf16x8*)&S.x2hi[l][0];
            s1a = (f32x4){w2b_c, w2b_c, w2b_c, w2b_c};
            s2a = (f32x4){w2b_c, w2b_c, w2b_c, w2b_c};
            s1a = MFMA(x1f, w2frag, s1a);
            s2a = MFMA(x2f, w2frag, s2a);
        }
#pragma unroll
        for (int i = 0; i < 4; ++i) {
            float r = sigm(gR[i]);
            float z = sigm(gZ[i]);
            float n = tanhf_(aN[i] + r * gN[i]);
            float hv = (1.0f - z) * n + z * h_reg[i];
            h_reg[i] = hv;
            S.hhi[ktH][hsB0 + i][eH] = f2bf(hv);
        }
        bar(); // h(t) visible
        // ---- P2: gh(t+1) carries + heads (LDS weights); in-reg attention -> c(t+1); x frags ----
        gR = (f32x4){bR, bR, bR, bR};
        gZ = (f32x4){bZ, bZ, bZ, bZ};
        gN = (f32x4){bhN, bhN, bhN, bhN};
        f32x4 whacc = {w1b_c, w1b_c, w1b_c, w1b_c};
#pragma unroll
        for (int kt = 0; kt < 4; ++kt) {
            bf16x8 hH = *(const bf16x8*)&S.hhi[kt][hsl][0];
            gR = MFMA(hH, whhR[0][kt], gR);
            gZ = MFMA(hH, whhR[1][kt], gZ);
            gN = MFMA(hH, whhR[2][kt], gN);
            if (w < 3) {
                bf16x8 hA = (w < 2) ? *(const bf16x8*)&S.w1f[w][kt][l][0]
                                    : *(const bf16x8*)&S.h2of[kt][l][0];
                whacc = MFMA(hH, hA, whacc);
            }
        }
        if (w == 2) {
            if (cl == 0) {
#pragma unroll
                for (int i = 0; i < 4; ++i)
                    out[(size_t)(b0 + 4 * g + i) * TSTEPS + t] = tanhf_(whacc[i] + h2ob);
            }
        } else if (isC) {   // waves 0,1: a1/a2 -> c(t+1) frags, fully in-register
#pragma unroll
            for (int i = 0; i < 4; ++i) {
                float v = whacc[i];
                float e1 = fexp(tanhf_(v + s1a[i]));
                float e2 = fexp(tanhf_(v + s2a[i]));
                float inv = frcp(e1 + e2);
                int row = 4 * g + i;
                float xh1 = S.xt[nxt][row][jC];
                float xh2 = S.xt[nxt][row][24 + jC];
                float cv = (e1 * inv) * xh1 + (e2 * inv) * xh2;
                u16 hi = f2bf(cv);
                S.chi[row + cSlotB][cEl] = hi;
                S.clo[row + cSlotB][cEl] = f2bf(cv - bf2f(hi));
            }
        }
        if (tid >= 128) {   // x(t+1) A-frags for next step's s1/s2 (384 threads)
            int e = tid - 128, rr = e & 15, j = e >> 4;
            float v1 = S.xt[nxt][rr][j];
            float v2 = S.xt[nxt][rr][24 + j];
            int slot = rr + (j >> 3) * 16, el = j & 7;
            S.x1hi[slot][el] = f2bf(v1);
            S.x2hi[slot][el] = f2bf(v2);
        }
        if (isLd) {         // store x(t+2) into the buffer that becomes xt[nxt] next step
            int e = tid - 320, row = e / 12, c4 = (e % 12) * 4;
            *(float4*)&S.xt[t & 1][row][c4] = xf;
        }
        bar(); // c/x frags + x(t+2) staged
    }
}

extern "C" void kernel_launch(void* const* d_in, const int* in_sizes, int n_in,
                              void* d_out, int out_size, void* d_ws, size_t ws_size,
                              hipStream_t stream) {
    const float* x    = (const float*)d_in[0];
    const float* wih  = (const float*)d_in[1];
    const float* whh  = (const float*)d_in[2];
    const float* bih  = (const float*)d_in[3];
    const float* bhh  = (const float*)d_in[4];
    const float* h2ow = (const float*)d_in[5];
    const float* h2ob = (const float*)d_in[6];
    const float* w1w  = (const float*)d_in[7];
    const float* w1b  = (const float*)d_in[8];
    const float* w2w  = (const float*)d_in[9];
    const float* w2b  = (const float*)d_in[10];
    float* out = (float*)d_out;

    gru_persist<<<NWG, NTHREADS, 0, stream>>>(x, wih, whh, bih, bhh,
                                              h2ow, h2ob, w1w, w1b, w2w, w2b, out);
}